// Round 5
// baseline (170.911 us; speedup 1.0000x reference)
//
#include <hip/hip_runtime.h>
#include <hip/hip_bf16.h>

// Problem dims (fixed): B=2, M=L=2048, H=1024, K_HEADS=16, D=64
// All inputs/output are FLOAT32; compute in bf16 MFMA with f32 accumulation.
// Algebra: softmax branch is dead; out = Q (K^T V) blockdiag Wo^T.
// Gram path: T_h = K_h^T V_h = Wk_h (hc^T hc) Wv_h^T:
//   G_b  = hcT_b @ hcT_b^T   (symmetric: 136 upper-tri tiles + transpose fill)
//   q_b  = h_b @ Wq^T        (INDEPENDENT of G chain -> fused in one dispatch)
//   T_h  = Wk_h G_b Wv_h^T   (fused, split over k'-tiles, atomics into Sbuf)
//   W2[n][h*64+dp] = sum_d Wo[n][h*64+d] T[h][dp][d]
//   out_b = q_b @ W2_b^T     (re-associated: h (W2 Wq)^T = (h Wq^T) W2^T)
// Round 14: double-buffered LDS NT body (prefetch tile t+1 before computing
// tile t; m99-verified pattern); mega_gq dispatch (q tiles give TLP cover for
// latency-bound G tiles); 5 dispatches total.
#define BB 2
#define MM 2048
#define HH 1024
#define KH 16

typedef short s16x8 __attribute__((ext_vector_type(8)));
typedef float f32x4 __attribute__((ext_vector_type(4)));
typedef float f32x16 __attribute__((ext_vector_type(16)));

#define GLOBAL_AS __attribute__((address_space(1)))
#define LDS_AS    __attribute__((address_space(3)))

__device__ __forceinline__ void async_copy16(const void* g, void* l) {
    __builtin_amdgcn_global_load_lds((const GLOBAL_AS void*)g, (LDS_AS void*)l, 16, 0, 0);
}

struct __align__(8) bf16x4_t { __hip_bfloat16 x, y, z, w; };

// ---------------------------------------------------------------------------
// fused prep: fp32->bf16 converts + hc transpose + Sbuf zero: grid (4096, 6)
// seg 0: convert h; seg 1: bx<1024 transpose-convert hc -> hcT, 1024<=bx<1152
//        zero Sbuf; seg 2/3/4: convert Wk/Wv/Wo; seg 5: convert Wq (plain)
// ---------------------------------------------------------------------------
__global__ __launch_bounds__(256) void cvt_all(
    const float* __restrict__ h_f, const float* __restrict__ hc_f,
    const float* __restrict__ Wk_f, const float* __restrict__ Wv_f,
    const float* __restrict__ Wo_f, const float* __restrict__ Wq_f,
    __hip_bfloat16* __restrict__ hb, __hip_bfloat16* __restrict__ hcT,
    __hip_bfloat16* __restrict__ wkb, __hip_bfloat16* __restrict__ wvb,
    __hip_bfloat16* __restrict__ wob, __hip_bfloat16* __restrict__ wqb,
    float* __restrict__ Sz)
{
    __shared__ float Tl[64][65];
    const int seg = blockIdx.y;
    const int t = threadIdx.x;
    const int bx = blockIdx.x;

    if (seg == 1) {
        if (bx < BB * 512) {               // hc -> hcT (per-b [1024][2048])
            const int b = bx >> 9;
            const int tile = bx & 511;
            const int m0 = (tile >> 4) * 64;   // 32 m-tiles
            const int k0 = (tile & 15) * 64;   // 16 k-tiles
            const int r = t >> 6;
            const int c = t & 63;
            const float* src = hc_f + (size_t)b * MM * HH;
#pragma unroll
            for (int i = 0; i < 64; i += 4)
                Tl[r + i][c] = src[(size_t)(m0 + r + i) * HH + k0 + c];
            __syncthreads();
            __hip_bfloat16* dst = hcT + (size_t)b * HH * MM;
            const int ml = (t & 15) * 4;
#pragma unroll
            for (int ii = 0; ii < 4; ++ii) {
                const int kl = (t >> 4) + 16 * ii;
                bf16x4_t o;
                o.x = __float2bfloat16(Tl[ml + 0][kl]);
                o.y = __float2bfloat16(Tl[ml + 1][kl]);
                o.z = __float2bfloat16(Tl[ml + 2][kl]);
                o.w = __float2bfloat16(Tl[ml + 3][kl]);
                *(bf16x4_t*)(dst + (size_t)(k0 + kl) * MM + m0 + ml) = o;
            }
        } else if (bx < BB * 512 + 128) {  // zero Sbuf: 131072 floats
            const int i = ((bx - BB * 512) * 256 + t) * 4;
            float4 z = {0.f, 0.f, 0.f, 0.f};
            *(float4*)(Sz + i) = z;
        }
        return;
    }
    const float* src;
    __hip_bfloat16* dst;
    int n;
    switch (seg) {
        case 0: src = h_f;  dst = hb;  n = BB * MM * HH; break;
        case 2: src = Wk_f; dst = wkb; n = HH * HH; break;
        case 3: src = Wv_f; dst = wvb; n = HH * HH; break;
        case 4: src = Wo_f; dst = wob; n = HH * HH; break;
        default: src = Wq_f; dst = wqb; n = HH * HH; break;
    }
    const int i = (bx * 256 + t) * 4;
    if (i + 3 < n) {
        const float4 v = *(const float4*)(src + i);
        bf16x4_t o;
        o.x = __float2bfloat16(v.x);
        o.y = __float2bfloat16(v.y);
        o.z = __float2bfloat16(v.z);
        o.w = __float2bfloat16(v.w);
        *(bf16x4_t*)(dst + i) = o;
    }
}

// ---------------------------------------------------------------------------
// store helpers
// ---------------------------------------------------------------------------
__device__ __forceinline__ void store_c(__hip_bfloat16* C, size_t idx, float v) {
    C[idx] = __float2bfloat16(v);
}
__device__ __forceinline__ void store_c(float* C, size_t idx, float v) { C[idx] = v; }

// ---------------------------------------------------------------------------
// 64x64-tile BK=64 NT GEMM body, DOUBLE-BUFFERED (m99-verified pattern):
// prefetch tile t+1 into buf^1 BEFORE computing tile t from buf, so the
// vmcnt(0) drain implicit in the end-of-iter __syncthreads overlaps the
// load latency with this tile's compute. One barrier per K-iter.
// As/Bs: 2 buffers x 8 KB each (16 KB per operand, 32 KB total).
// 4 waves, each one 32x32 quadrant. A/B pre-offset to tile origin.
// ---------------------------------------------------------------------------
__device__ __forceinline__ f32x16 nt64_db_acc(
    const __hip_bfloat16* __restrict__ A, const __hip_bfloat16* __restrict__ B,
    int kd, size_t ld, __hip_bfloat16* As, __hip_bfloat16* Bs)
{
    const int t    = threadIdx.x;
    const int lane = t & 63;
    const int wave = t >> 6;
    const int srow = lane >> 3;
    const int sw   = ((lane & 7) ^ srow) * 8;
    const int wm   = (wave >> 1) * 32;
    const int wn   = (wave & 1) * 32;
    const int fm   = lane & 31;
    const int fm7  = fm & 7;
    const int ghi  = lane >> 5;

    // prologue: stage tile 0 into buffer 0
#pragma unroll
    for (int i = 0; i < 2; ++i) {
        const int c = wave * 2 + i;
        async_copy16(A + (size_t)(c * 8 + srow) * ld + sw, As + c * 512);
        async_copy16(B + (size_t)(c * 8 + srow) * ld + sw, Bs + c * 512);
    }
    __syncthreads();   // tile 0 landed (vmcnt(0) implicit)

    f32x16 acc = {};
    int cur = 0;
    for (int k0 = 0; k0 < kd; k0 += 64) {
        const int nxt = cur ^ 1;
        if (k0 + 64 < kd) {   // issue next-tile loads into the other buffer
#pragma unroll
            for (int i = 0; i < 2; ++i) {
                const int c = wave * 2 + i;
                async_copy16(A + (size_t)(c * 8 + srow) * ld + (k0 + 64) + sw,
                             As + nxt * 4096 + c * 512);
                async_copy16(B + (size_t)(c * 8 + srow) * ld + (k0 + 64) + sw,
                             Bs + nxt * 4096 + c * 512);
            }
        }
#pragma unroll
        for (int ks = 0; ks < 64; ks += 16) {
            const int pos = ((((ks >> 3) + ghi) ^ fm7) * 8);
            const s16x8 af = *(const s16x8*)(As + cur * 4096 + (wm + fm) * 64 + pos);
            const s16x8 bf = *(const s16x8*)(Bs + cur * 4096 + (wn + fm) * 64 + pos);
            acc = __builtin_amdgcn_mfma_f32_32x32x16_bf16(af, bf, acc, 0, 0, 0);
        }
        __syncthreads();   // next tile landed; all waves done reading cur
        cur = nxt;
    }
    return acc;
}

// direct store of the 64x64 tile (C pre-offset to tile origin)
template <typename OutT>
__device__ __forceinline__ void store_tile64(OutT* C, int ldc, const f32x16& acc) {
    const int lane = threadIdx.x & 63;
    const int wave = threadIdx.x >> 6;
    const int wm = (wave >> 1) * 32;
    const int wn = (wave & 1) * 32;
    const int col = wn + (lane & 31);
    const int rb  = 4 * (lane >> 5);
#pragma unroll
    for (int r = 0; r < 16; ++r) {
        const int row = wm + (r & 3) + 8 * (r >> 2) + rb;
        store_c(C, (size_t)row * ldc + col, acc[r]);
    }
}

// ---------------------------------------------------------------------------
// MEGA dispatch: q-projection tiles + Gram tiles in ONE kernel.
// grid (648, 1, BB):
//   bx <  512: q_b tile  (q = h @ Wq^T, NT, K=1024)      [32 x 16 tiles]
//   bx >= 512: G_b upper-tri tile (G = hcT @ hcT^T, K=2048) + transpose fill
// The 1024 q-blocks provide TLP cover for the 272 latency-bound G-blocks.
// ---------------------------------------------------------------------------
__global__ __launch_bounds__(256) void mega_gq(
    const __hip_bfloat16* __restrict__ hb, const __hip_bfloat16* __restrict__ wqb,
    const __hip_bfloat16* __restrict__ hcT,
    __hip_bfloat16* __restrict__ qb, __hip_bfloat16* __restrict__ G)
{
    __shared__ __align__(16) char smem[32768];
    __hip_bfloat16* As = (__hip_bfloat16*)smem;             // 16 KB (2 bufs)
    __hip_bfloat16* Bs = (__hip_bfloat16*)(smem + 16384);   // 16 KB (2 bufs)
    __hip_bfloat16* Ts = (__hip_bfloat16*)smem;             // 64x72 bounce

    const int b = blockIdx.z;
    const int bx = blockIdx.x;

    if (bx < 512) {                        // q tile
        const int m0 = (bx >> 4) * 64, n0 = (bx & 15) * 64;
        f32x16 acc = nt64_db_acc(hb + (size_t)b * MM * HH + (size_t)m0 * HH,
                                 wqb + (size_t)n0 * HH, HH, HH, As, Bs);
        store_tile64(qb + (size_t)b * MM * HH + (size_t)m0 * HH + n0, HH, acc);
        return;
    }

    // G upper-tri tile: decode (i<=j) from bx-512 in [0,136)
    int i = 0, rem = bx - 512;
    while (rem >= 16 - i) { rem -= 16 - i; ++i; }
    const int j = i + rem;
    const int m0 = i * 64, n0 = j * 64;

    const __hip_bfloat16* Ab = hcT + (size_t)b * HH * MM;
    f32x16 acc = nt64_db_acc(Ab + (size_t)m0 * MM, Ab + (size_t)n0 * MM, MM, MM, As, Bs);

    __hip_bfloat16* Gb = G + (size_t)b * HH * HH;
    store_tile64(Gb + (size_t)m0 * HH + n0, HH, acc);

    if (i == j) return;

    // transpose fill of tile (j,i) via LDS bounce
    __syncthreads();   // all waves done with As before Ts overwrite
    {
        const int lane = threadIdx.x & 63;
        const int wave = threadIdx.x >> 6;
        const int wm = (wave >> 1) * 32;
        const int wn = (wave & 1) * 32;
        const int col = wn + (lane & 31);
        const int rb  = 4 * (lane >> 5);
#pragma unroll
        for (int r = 0; r < 16; ++r) {
            const int row = wm + (r & 3) + 8 * (r >> 2) + rb;
            Ts[row * 72 + col] = __float2bfloat16(acc[r]);
        }
    }
    __syncthreads();
    {
        const int t = threadIdx.x;
        const int rp = t >> 2;            // 0..63: row of transposed tile
        const int c0 = (t & 3) * 16;      // 16 cols per thread
        __hip_bfloat16* dst = Gb + (size_t)(n0 + rp) * HH + m0 + c0;
#pragma unroll
        for (int kk = 0; kk < 4; ++kk) {
            bf16x4_t o;
            o.x = Ts[(c0 + 4 * kk + 0) * 72 + rp];
            o.y = Ts[(c0 + 4 * kk + 1) * 72 + rp];
            o.z = Ts[(c0 + 4 * kk + 2) * 72 + rp];
            o.w = Ts[(c0 + 4 * kk + 3) * 72 + rp];
            *(bf16x4_t*)(dst + 4 * kk) = o;
        }
    }
}

// ---------------------------------------------------------------------------
// FUSED T_h = Wk_h G_b Wv_h^T, split over k'-tiles: grid (16, KH, BB) = 512
// Stage 1: Q[cc][i] = sum_k G[kt*64+cc][k] Wk_h[i][k]   (NT, K=1024, dbuf)
// Stage 2: T[i][j] += sum_cc Q^T[i][cc] Wv_h[j][kt*64+cc] (16x16x32 MFMA)
// atomicAdd partials into Sbuf (zeroed by cvt). Verified rounds 8/11-13.
// ---------------------------------------------------------------------------
#define LPP 72

__global__ __launch_bounds__(256) void gemm_vt(
    const __hip_bfloat16* __restrict__ wkb, const __hip_bfloat16* __restrict__ wvb,
    const __hip_bfloat16* __restrict__ G, float* __restrict__ S)
{
    __shared__ __align__(16) char smem[32768];
    __hip_bfloat16* As = (__hip_bfloat16*)smem;             // 16 KB (stage 1)
    __hip_bfloat16* Bs = (__hip_bfloat16*)(smem + 16384);   // 16 KB (stage 1)
    __hip_bfloat16* Pl = (__hip_bfloat16*)smem;             // 64 x LPP (stage 2)
    __hip_bfloat16* Wl = (__hip_bfloat16*)(smem + 64 * LPP * 2);  // 64x64 swz

    const int t    = threadIdx.x;
    const int lane = t & 63;
    const int wave = t >> 6;
    const int kt   = blockIdx.x;
    const int head = blockIdx.y;
    const int b    = blockIdx.z;

    const __hip_bfloat16* Arow = G + (size_t)b * HH * HH + (size_t)kt * 64 * HH;
    const __hip_bfloat16* Brow = wkb + (size_t)head * 64 * HH;

    f32x16 acc = nt64_db_acc(Arow, Brow, HH, HH, As, Bs);
    __syncthreads();   // all waves done reading As/Bs before Pl/Wl overwrite

    // Q[cc][i] -> Pl[i][cc] (4 consecutive cc per bf16x4, contiguous)
    {
        const int wm = (wave >> 1) * 32;     // cc quadrant
        const int wn = (wave & 1) * 32;      // i quadrant
        const int col_i = wn + (lane & 31);
        const int ghi4  = 4 * (lane >> 5);
#pragma unroll
        for (int g = 0; g < 4; ++g) {
            const int ccb = wm + 8 * g + ghi4;
            bf16x4_t o;
            o.x = __float2bfloat16(acc[4 * g + 0]);
            o.y = __float2bfloat16(acc[4 * g + 1]);
            o.z = __float2bfloat16(acc[4 * g + 2]);
            o.w = __float2bfloat16(acc[4 * g + 3]);
            *(bf16x4_t*)(Pl + col_i * LPP + ccb) = o;
        }
    }
    // stage Wv_h[:, kt-tile] (64x64) with pre-swizzled source columns
    {
        const int srow = lane >> 3;
        const int sw   = ((lane & 7) ^ srow) * 8;
#pragma unroll
        for (int i = 0; i < 2; ++i) {
            const int c = wave * 2 + i;
            async_copy16(wvb + (size_t)(head * 64 + c * 8 + srow) * HH + kt * 64 + sw,
                         Wl + c * 512);
        }
    }
    __syncthreads();

    const int fr  = lane & 15;
    const int fq  = (lane >> 4) * 8;
    const int wm2 = wave * 16;

    f32x4 acc2[4] = {};
#pragma unroll
    for (int kk = 0; kk < 64; kk += 32) {
        const s16x8 af = *(const s16x8*)(Pl + (wm2 + fr) * LPP + kk + fq);
#pragma unroll
        for (int nj = 0; nj < 4; ++nj) {
            const int row = nj * 16 + fr;
            const s16x8 bfv = *(const s16x8*)(
                Wl + row * 64 + ((((kk + fq) >> 3) ^ (row & 7)) << 3));
            acc2[nj] = __builtin_amdgcn_mfma_f32_16x16x32_bf16(af, bfv, acc2[nj], 0, 0, 0);
        }
    }

    float* Sg = S + ((size_t)b * KH + head) * 4096;
    const int er = (lane >> 4) * 4;
    const int ec = lane & 15;
#pragma unroll
    for (int nj = 0; nj < 4; ++nj)
#pragma unroll
        for (int rr = 0; rr < 4; ++rr)
            atomicAdd(&Sg[(wm2 + er + rr) * 64 + nj * 16 + ec], acc2[nj][rr]);
}

// ---------------------------------------------------------------------------
// out_b = q_b @ W2_b^T, fp32 out: grid (512, 1, BB)
// ---------------------------------------------------------------------------
__global__ __launch_bounds__(256) void gemm_final2(
    const __hip_bfloat16* __restrict__ qb, const __hip_bfloat16* __restrict__ W2,
    float* __restrict__ outg)
{
    __shared__ __align__(16) char smem[32768];
    __hip_bfloat16* As = (__hip_bfloat16*)smem;
    __hip_bfloat16* Bs = (__hip_bfloat16*)(smem + 16384);
    const int b = blockIdx.z;
    const int m0 = (blockIdx.x >> 4) * 64, n0 = (blockIdx.x & 15) * 64;
    f32x16 acc = nt64_db_acc(qb + (size_t)b * MM * HH + (size_t)m0 * HH,
                             W2 + (size_t)b * HH * HH + (size_t)n0 * HH,
                             HH, HH, As, Bs);
    store_tile64(outg + (size_t)b * MM * HH + (size_t)m0 * HH + n0, HH, acc);
}

// ---------------------------------------------------------------------------
// W2[b][n][h*64+dp] = sum_d Wo[n][h*64+d] * T[b,h,dp,d]   (bf16 out)
// grid (8, KH, BB), block 256  (verified rounds 2-13)
// ---------------------------------------------------------------------------
__global__ __launch_bounds__(256) void w2_fold(
    const __hip_bfloat16* __restrict__ Wo,
    const float* __restrict__ S,
    __hip_bfloat16* __restrict__ W2)
{
    __shared__ float Sl[64 * 68];
    __shared__ float Wl[128 * 68];
    const int t = threadIdx.x, head = blockIdx.y, b = blockIdx.z;
    const int n0 = blockIdx.x * 128;

    const float* Sg = S + ((size_t)b * KH + head) * 4096;
    for (int idx = t; idx < 4096; idx += 256) {
        const int dp = idx >> 6, d = idx & 63;
        Sl[d * 68 + dp] = Sg[idx];
    }
    for (int idx = t; idx < 1024; idx += 256) {
        const int r = idx >> 3, c8 = (idx & 7) * 8;
        s16x8 wv = *(const s16x8*)(Wo + (size_t)(n0 + r) * HH + head * 64 + c8);
#pragma unroll
        for (int j = 0; j < 8; ++j) {
            __hip_bfloat16 wb = *(((const __hip_bfloat16*)&wv) + j);
            Wl[r * 68 + c8 + j] = __bfloat162float(wb);
        }
    }
    __syncthreads();

    const int dpb = (t & 15) * 4;
    const int ng  = t >> 4;
    float acc[8][4] = {};
    for (int d0 = 0; d0 < 64; d0 += 4) {
        f32x4 sv[4];
#pragma unroll
        for (int r = 0; r < 4; ++r)
            sv[r] = *(const f32x4*)(Sl + (d0 + r) * 68 + dpb);
#pragma unroll
        for (int i = 0; i < 8; ++i) {
            const f32x4 wv = *(const f32x4*)(Wl + (ng + 16 * i) * 68 + d0);
#pragma unroll
            for (int r = 0; r < 4; ++r)
#pragma unroll
                for (int j = 0; j < 4; ++j)
                    acc[i][j] += wv[r] * sv[r][j];
        }
    }

#pragma unroll
    for (int i = 0; i < 8; ++i) {
        bf16x4_t o;
        o.x = __float2bfloat16(acc[i][0]);
        o.y = __float2bfloat16(acc[i][1]);
        o.z = __float2bfloat16(acc[i][2]);
        o.w = __float2bfloat16(acc[i][3]);
        *(bf16x4_t*)(W2 + (size_t)b * HH * HH + (size_t)(n0 + ng + 16 * i) * HH
                     + head * 64 + dpb) = o;
    }
}

// ---------------------------------------------------------------------------
extern "C" void kernel_launch(void* const* d_in, const int* in_sizes, int n_in,
                              void* d_out, int out_size, void* d_ws, size_t ws_size,
                              hipStream_t stream) {
    const float* h_f  = (const float*)d_in[0];
    const float* hc_f = (const float*)d_in[1];
    // d_in[2] = key_pe: DEAD (softmax result unused by reference output)
    const float* Wq_f = (const float*)d_in[3];
    const float* Wk_f = (const float*)d_in[4];
    const float* Wv_f = (const float*)d_in[5];
    const float* Wo_f = (const float*)d_in[6];
    float* out = (float*)d_out;

    const size_t act_b = (size_t)BB * MM * HH * 2;  // 8 MB
    const size_t w_b   = (size_t)HH * HH * 2;       // 2 MB
    char* ws = (char*)d_ws;
    __hip_bfloat16* hb   = (__hip_bfloat16*)(ws);                       // 8 MB
    __hip_bfloat16* hcT  = (__hip_bfloat16*)(ws + act_b);               // 8 MB ([b][k][m])
    __hip_bfloat16* wkb  = (__hip_bfloat16*)(ws + 2 * act_b);           // 2 MB
    __hip_bfloat16* wvb  = (__hip_bfloat16*)(ws + 2 * act_b + w_b);     // 2 MB
    __hip_bfloat16* wob  = (__hip_bfloat16*)(ws + 2 * act_b + 2 * w_b); // 2 MB
    __hip_bfloat16* wqb  = (__hip_bfloat16*)(ws + 2 * act_b + 3 * w_b); // 2 MB
    __hip_bfloat16* qb   = (__hip_bfloat16*)(ws + 2 * act_b + 4 * w_b); // 8 MB
    __hip_bfloat16* Gb   = (__hip_bfloat16*)(ws + 3 * act_b + 4 * w_b); // 4 MB
    float*          Sbuf = (float*)(ws + 3 * act_b + 6 * w_b);          // 512 KB
    __hip_bfloat16* W2   = (__hip_bfloat16*)(ws + 3 * act_b + 6 * w_b + (size_t)512 * 1024);  // 4 MB

    const dim3 blk(256);

    // 0: all prep in one dispatch (converts + hc transpose + Sbuf zero)
    cvt_all<<<dim3(4096, 6), blk, 0, stream>>>(h_f, hc_f, Wk_f, Wv_f, Wo_f, Wq_f,
                                               hb, hcT, wkb, wvb, wob, wqb, Sbuf);

    // 1: MEGA: q = h Wq^T (1024 blocks) + G = hcT hcT^T symmetric (272 blocks)
    mega_gq<<<dim3(648, 1, BB), blk, 0, stream>>>(hb, wqb, hcT, qb, Gb);

    // 2: T_h = Wk_h G_b Wv_h^T fused (atomic partials into zeroed Sbuf)
    gemm_vt<<<dim3(16, KH, BB), blk, 0, stream>>>(wkb, wvb, Gb, Sbuf);

    // 3: W2 = blockdiag(T) folded into Wo
    w2_fold<<<dim3(8, KH, BB), blk, 0, stream>>>(wob, Sbuf, W2);

    // 4: out = q @ W2^T (fp32 out)
    gemm_final2<<<dim3(512, 1, BB), blk, 0, stream>>>(qb, W2, out);
}